// Round 4
// baseline (684.483 us; speedup 1.0000x reference)
//
#include <hip/hip_runtime.h>

// QRNN-fo layer. Dtype model v3: inputs FP32, output FP32.
// Evidence: (1) fp32-as-bf16 read => NaN (round 1) so inputs are fp32;
// (2) rounds 2/3 (bf16-MFMA vs fp32-VALU GEMM) gave IDENTICAL absmax
// 1.597656 => both GEMMs correct, shared assumption wrong; (3) the "(bf16"
// in the assert label is hard-coded format text, not the executed decode
// branch; reference output dtype is fp32 and the template says d_out follows
// the reference. Packed-bf16 H decoded as fp32 predicts exactly the observed
// bounded O(1) error.
//
// Pipeline:
//   K0a: X fp32->bf16 into d_out's H region (64 MiB of the 128 MiB region;
//        consumed by GEMM, then overwritten by the scan)
//   K0b: W fp32->bf16 into ws after Y
//   K1 : bf16 MFMA GEMM Y = act(X @ W^T + b)  -> bf16 Y in ws (192 MiB)
//   K2 : sequential scan -> fp32 H (2048,16,1024) ++ fp32 C_last (1,16,1024)

#define S_LEN 2048
#define BATCH 16
#define DHID 1024
#define N3 3072               // 3*DHID
#define MROWS (S_LEN * BATCH) // 32768
#define XELEMS ((size_t)MROWS * DHID)   // 33,554,432
#define WELEMS ((size_t)N3 * DHID)      //  3,145,728
#define YELEMS ((size_t)MROWS * N3)     // 100,663,296

typedef __attribute__((ext_vector_type(8))) short bf16x8;
typedef __attribute__((ext_vector_type(4))) float floatx4;
typedef __attribute__((ext_vector_type(4))) unsigned short u16x4;

__device__ __forceinline__ float b2f(unsigned short u) {
  return __uint_as_float(((unsigned)u) << 16);
}
__device__ __forceinline__ unsigned short f2b(float x) {
  unsigned u = __float_as_uint(x);
  u += 0x7fffu + ((u >> 16) & 1u);   // round-to-nearest-even
  return (unsigned short)(u >> 16);
}
__device__ __forceinline__ float sigmoid_f(float x) {
  return __builtin_amdgcn_rcpf(1.0f + __expf(-x));
}
__device__ __forceinline__ float tanh_f(float x) {
  return 2.0f * __builtin_amdgcn_rcpf(1.0f + __expf(-2.0f * x)) - 1.0f;
}

__device__ __forceinline__ void load_lds16(const unsigned short* g, unsigned short* l) {
  __builtin_amdgcn_global_load_lds(
      (const __attribute__((address_space(1))) void*)g,
      (__attribute__((address_space(3))) void*)l,
      16, 0, 0);
}

// ---------------------------------------------------------------------------
// fp32 -> bf16 converter (vectorized, n multiple of 4)
// ---------------------------------------------------------------------------
__global__ __launch_bounds__(256) void cvt_f32_bf16(
    const float* __restrict__ src, unsigned short* __restrict__ dst, int n4) {
  int i = blockIdx.x * 256 + threadIdx.x;
  if (i < n4) {
    float4 v = ((const float4*)src)[i];
    u16x4 o;
    o.x = f2b(v.x); o.y = f2b(v.y); o.z = f2b(v.z); o.w = f2b(v.w);
    ((u16x4*)dst)[i] = o;
  }
}

// ---------------------------------------------------------------------------
// GEMM: Y[m][n] = act( sum_k X[m][k]*W[n][k] + b[n] ), bf16 store.
// 128x128 block tile, 4 waves (2x2), each wave 64x64 via 4x4 MFMA 16x16x32.
// BK=64, single-buffered LDS via global_load_lds width 16 (m97 structure).
// Validated by agreement with the round-3 fp32 VALU GEMM (identical absmax).
// ---------------------------------------------------------------------------
__global__ __launch_bounds__(256) void qrnn_gemm(
    const unsigned short* __restrict__ X,    // (32768,1024) bf16 (converted)
    const unsigned short* __restrict__ W,    // (3072,1024)  bf16 (converted)
    const float* __restrict__ bias,          // (3072)       fp32
    unsigned short* __restrict__ Y)          // (32768,3072) bf16 activated
{
  __shared__ __align__(16) unsigned short sA[128 * 64];
  __shared__ __align__(16) unsigned short sB[128 * 64];

  const int tid = threadIdx.x;
  const int w  = tid >> 6;     // wave 0..3
  const int l  = tid & 63;     // lane
  const int lr = l & 15;
  const int lq = l >> 4;
  const int n0B = blockIdx.x * 128;
  const int m0B = blockIdx.y * 128;
  const int wm = (w >> 1) * 64;
  const int wn = (w & 1) * 64;

  floatx4 acc[4][4] = {};

  const unsigned short* gA = X + (size_t)m0B * DHID;
  const unsigned short* gB = W + (size_t)n0B * DHID;
  const int srow = tid >> 3;           // 0..31 within 32-row chunk
  const int scol = (tid & 7) << 3;     // 0..56 step 8 shorts (16 B)

  for (int k0 = 0; k0 < DHID; k0 += 64) {
#pragma unroll
    for (int j = 0; j < 4; ++j) {
      // LDS dest = wave-uniform base + lane*16B; linear chunk order equals
      // [row][k] row-major, no padding.
      load_lds16(gA + (size_t)(j * 32 + srow) * DHID + (k0 + scol),
                 sA + (j * 2048 + w * 512));
      load_lds16(gB + (size_t)(j * 32 + srow) * DHID + (k0 + scol),
                 sB + (j * 2048 + w * 512));
    }
    __syncthreads();

#pragma unroll
    for (int kk = 0; kk < 64; kk += 32) {
      bf16x8 af[4], bf[4];
#pragma unroll
      for (int i = 0; i < 4; ++i) {
        af[i] = *(const bf16x8*)&sA[(wm + i * 16 + lr) * 64 + kk + lq * 8];
      }
#pragma unroll
      for (int j = 0; j < 4; ++j) {
        bf[j] = *(const bf16x8*)&sB[(wn + j * 16 + lr) * 64 + kk + lq * 8];
      }
#pragma unroll
      for (int i = 0; i < 4; ++i) {
#pragma unroll
        for (int j = 0; j < 4; ++j) {
          acc[i][j] = __builtin_amdgcn_mfma_f32_16x16x32_bf16(
              af[i], bf[j], acc[i][j], 0, 0, 0);
        }
      }
    }
    __syncthreads();
  }

  // Epilogue. C/D layout: col = lane&15, row = quad*4 + reg (m89/m91).
  const int seg = n0B >> 10;   // 0:Z(tanh) 1:F(sigmoid) 2:O(sigmoid)
#pragma unroll
  for (int j = 0; j < 4; ++j) {
    const int n = n0B + wn + j * 16 + lr;
    const float bv = bias[n];
#pragma unroll
    for (int i = 0; i < 4; ++i) {
      const int mb = m0B + wm + i * 16 + lq * 4;
#pragma unroll
      for (int r = 0; r < 4; ++r) {
        float v = acc[i][j][r] + bv;
        v = (seg == 0) ? tanh_f(v) : sigmoid_f(v);
        Y[(size_t)(mb + r) * N3 + n] = f2b(v);
      }
    }
  }
}

// ---------------------------------------------------------------------------
// Scan: per (b,d) chain. c = f*z + (1-f)*c ; h = sig(o)*c (o pre-activated).
// 16384 threads = 256 blocks x 64. Chunks of 8 steps, depth-2 reg prefetch.
// FP32 output this round.
// ---------------------------------------------------------------------------
#define U 8
#define NCH (S_LEN / U)            // 256
#define SSTRIDE (BATCH * N3)       // 49152
#define HSTRIDE (BATCH * DHID)     // 16384

__global__ __launch_bounds__(64) void qrnn_scan(
    const unsigned short* __restrict__ Y,
    const float* __restrict__ h0,            // (16,1024) fp32
    float* __restrict__ out)                 // H (2048,16,1024) ++ C_last fp32
{
  const int t = blockIdx.x * 64 + threadIdx.x;   // 0..16383
  const int b = t >> 10;
  const int d = t & 1023;
  const unsigned short* base = Y + (size_t)b * N3 + d;
  float* ho = out + (size_t)b * DHID + d;
  float c = h0[t];

  unsigned short z0[U], f0[U], o0[U], z1[U], f1[U], o1[U];

#define LOADCH(ch, zz, ff, oo) { \
    const unsigned short* p = base + (size_t)(ch) * ((size_t)U * SSTRIDE); \
    _Pragma("unroll") \
    for (int j2 = 0; j2 < U; ++j2) { \
      zz[j2] = p[(size_t)j2 * SSTRIDE]; \
      ff[j2] = p[(size_t)j2 * SSTRIDE + DHID]; \
      oo[j2] = p[(size_t)j2 * SSTRIDE + 2 * DHID]; \
    } }

#define COMPCH(ch, zz, ff, oo) { \
    float* q = ho + (size_t)(ch) * ((size_t)U * HSTRIDE); \
    _Pragma("unroll") \
    for (int j2 = 0; j2 < U; ++j2) { \
      float zv = b2f(zz[j2]); \
      float fv = b2f(ff[j2]); \
      float ov = b2f(oo[j2]); \
      c = fmaf(fv, zv - c, c); \
      q[(size_t)j2 * HSTRIDE] = ov * c; \
    } }

  LOADCH(0, z0, f0, o0);
  for (int ch = 0; ch < NCH; ch += 2) {
    LOADCH(ch + 1, z1, f1, o1);
    COMPCH(ch, z0, f0, o0);
    if (ch + 2 < NCH) LOADCH(ch + 2, z0, f0, o0);
    COMPCH(ch + 1, z1, f1, o1);
  }
  out[(size_t)S_LEN * HSTRIDE + t] = c;   // C_last fp32
}

// ---------------------------------------------------------------------------
extern "C" void kernel_launch(void* const* d_in, const int* in_sizes, int n_in,
                              void* d_out, int out_size, void* d_ws, size_t ws_size,
                              hipStream_t stream) {
  const float* X    = (const float*)d_in[0]; // (2048,16,1024) fp32
  const float* h0   = (const float*)d_in[1]; // (16,1024)      fp32
  const float* W    = (const float*)d_in[2]; // (3072,1024)    fp32
  const float* bias = (const float*)d_in[3]; // (3072)         fp32
  float* out = (float*)d_out;                // fp32 H ++ C_last (128.06 MiB)

  // ws: Y bf16 (192 MiB) ++ Wbf (6 MiB). Xbf (64 MiB) parks in d_out's
  // H region (128 MiB fp32) and is consumed before the scan rewrites it.
  unsigned short* Ybf = (unsigned short*)d_ws;
  unsigned short* Wbf = Ybf + YELEMS;
  unsigned short* Xbf = (unsigned short*)out;

  cvt_f32_bf16<<<(int)(XELEMS / 4 + 255) / 256, 256, 0, stream>>>(X, Xbf, (int)(XELEMS / 4));
  cvt_f32_bf16<<<(int)(WELEMS / 4 + 255) / 256, 256, 0, stream>>>(W, Wbf, (int)(WELEMS / 4));
  qrnn_gemm<<<dim3(N3 / 128, MROWS / 128), 256, 0, stream>>>(Xbf, Wbf, bias, Ybf);
  qrnn_scan<<<dim3((BATCH * DHID) / 64), 64, 0, stream>>>(Ybf, h0, out);
}